// Round 11
// baseline (2687.949 us; speedup 1.0000x reference)
//
#include <hip/hip_runtime.h>

// VonMisesNet: B=128, V=128, F=40, H=256, L=32, FL=1024, OUT=1
#define Bsz 128
#define Vn  128
#define Fdim 40
#define Hdim 256
#define Lnum 32
#define FLdim 1024
#define LN_EPS 1e-5f

typedef unsigned short u16;
typedef __attribute__((ext_vector_type(8))) short short8;
typedef __attribute__((ext_vector_type(4))) float f32x4;

__device__ __forceinline__ u16 f2bf(float f) {
    unsigned u = __float_as_uint(f);
    u += 0x7fff + ((u >> 16) & 1);          // round-to-nearest-even
    return (u16)(u >> 16);
}
__device__ __forceinline__ float bf2f(u16 s) {
    return __uint_as_float((unsigned)s << 16);
}

__device__ __forceinline__ void split4(const f32x4& f, ushort4& h4, ushort4& l4) {
    u16 h0 = f2bf(f[0]), h1 = f2bf(f[1]), h2 = f2bf(f[2]), h3 = f2bf(f[3]);
    h4.x = h0; h4.y = h1; h4.z = h2; h4.w = h3;
    l4.x = f2bf(f[0] - bf2f(h0));
    l4.y = f2bf(f[1] - bf2f(h1));
    l4.z = f2bf(f[2] - bf2f(h2));
    l4.w = f2bf(f[3] - bf2f(h3));
}

// ---------------- rowsum: n[m] = sum_j G[m,j]; invdeg = 1/(n + (n==0)) ----------------
__global__ __launch_bounds__(256) void rowsum_kernel(const float* __restrict__ G,
                                                     float* __restrict__ nrow,
                                                     float* __restrict__ invdeg) {
    int row = blockIdx.x * 4 + (threadIdx.x >> 6);
    int lane = threadIdx.x & 63;
    const float* g = G + (size_t)row * Vn;
    float s = g[lane] + g[lane + 64];
    #pragma unroll
    for (int off = 32; off; off >>= 1) s += __shfl_down(s, off);
    if (lane == 0) {
        nrow[row] = s;
        invdeg[row] = 1.0f / (s + (s == 0.0f ? 1.0f : 0.0f));
    }
}

// ---------------- Gbf[b][i][j] = bf16(G + diag(n)) (exact: 0/1/int) ----------------
__global__ __launch_bounds__(256) void gbf_kernel(const float* __restrict__ G,
                                                  const float* __restrict__ nrow,
                                                  u16* __restrict__ gbf) {
    int gid = blockIdx.x * 256 + threadIdx.x;      // handles 8 j's
    int j8 = gid & 15;
    int m  = gid >> 4;                             // b*128 + i
    int i  = m & 127;
    const float* src = G + (size_t)m * Vn + j8 * 8;
    float4 g0 = *(const float4*)src;
    float4 g1 = *(const float4*)(src + 4);
    float nb = nrow[m];
    float ge[8] = {g0.x, g0.y, g0.z, g0.w, g1.x, g1.y, g1.z, g1.w};
    u16 us[8];
    #pragma unroll
    for (int e = 0; e < 8; ++e) {
        float val = ge[e] + ((j8 * 8 + e) == i ? nb : 0.0f);
        us[e] = f2bf(val);
    }
    uint4 pack;
    pack.x = (unsigned)us[0] | ((unsigned)us[1] << 16);
    pack.y = (unsigned)us[2] | ((unsigned)us[3] << 16);
    pack.z = (unsigned)us[4] | ((unsigned)us[5] << 16);
    pack.w = (unsigned)us[6] | ((unsigned)us[7] << 16);
    *(uint4*)(gbf + (size_t)m * Vn + j8 * 8) = pack;
}

// ------------- transpose+split: src[K][N] f32 -> hi/lo[N][K] bf16 (per blockIdx.z mat) -------------
__global__ __launch_bounds__(256) void tsplit_kernel(const float* __restrict__ src,
                                                     u16* __restrict__ hi, u16* __restrict__ lo,
                                                     int N, int K) {
    __shared__ float tl[64][65];
    size_t mat = (size_t)blockIdx.z * K * N;
    int k0 = blockIdx.x * 64, n0 = blockIdx.y * 64;
    int t = threadIdx.x, c = t & 63, r4 = t >> 6;
    #pragma unroll
    for (int i = 0; i < 16; ++i) {
        int r = i * 4 + r4;
        tl[r][c] = src[mat + (size_t)(k0 + r) * N + n0 + c];
    }
    __syncthreads();
    #pragma unroll
    for (int i = 0; i < 16; ++i) {
        int nr = i * 4 + r4;
        float val = tl[c][nr];
        u16 h = f2bf(val);
        size_t idx = mat + (size_t)(n0 + nr) * K + k0 + c;
        hi[idx] = h;
        lo[idx] = f2bf(val - bf2f(h));
    }
}

// ---------------- feat: v = x@W_feat + b_feat (fp32 master only) ----------------
__global__ __launch_bounds__(256) void feat_kernel(const float* __restrict__ x,
                                                   const float* __restrict__ Wf,
                                                   const float* __restrict__ bf,
                                                   float* __restrict__ v) {
    __shared__ float xs[Fdim];
    int row = blockIdx.x;
    int h = threadIdx.x;
    if (h < Fdim) xs[h] = x[(size_t)row * Fdim + h];
    __syncthreads();
    float acc = bf[h];
    #pragma unroll 8
    for (int f = 0; f < Fdim; ++f) acc += xs[f] * Wf[f * Hdim + h];
    v[(size_t)row * Hdim + h] = acc;
}

// ================= ALL 32 LAYERS, one kernel, 1024 threads (16 waves) per batch-block ======
// Wave roles: wlo = w&1 (d-half of 128), whi = w>>1 (0..7, 16-row i/j-group).
// Per-thread state halved vs R8-R10 so it FITS the 128-VGPR budget the backend insists on:
//   vreg[8] (32) + acc[8] (32, GEMM1/GEMM2 lifetimes disjoint) + transients ~ 110 regs.
// G lives in a 32KB LDS region (parked once), not registers.
// LDS 160KB: As (2x64K, [128 j][512B]) aliases VP (2x64K, [256 d][256B]); Gs 32K @131072.
// Swizzle everywhere: byte ^ ((row&15)<<4) == byte ^ (lr<<4) (all tile rows ≡ lr mod 16).
__global__ __attribute__((amdgpu_flat_work_group_size(1024, 1024)))
void layers_all(float* __restrict__ v_io,
                const u16* __restrict__ wthi_all,
                const u16* __restrict__ wtlo_all,
                const float* __restrict__ b_all,
                const u16* __restrict__ gbf,
                const float* __restrict__ invdeg) {
    extern __shared__ char smem[];
    char* AsH = smem;                // 64K [128 j][512B]
    char* AsL = smem + 65536;        // 64K
    char* VPH = smem;                // alias: 64K [256 d][256B]
    char* VPL = smem + 65536;        // alias
    char* Gs  = smem + 131072;       // 32K [128 i][256B]

    const int tid = threadIdx.x, l = tid & 63, w = tid >> 6;
    const int wlo = w & 1, whi = w >> 1;
    const int b = blockIdx.x;
    const int lr = l & 15, lq = l >> 4;
    const int sw = lr << 4;

    // ---- park Gs once (swizzled); consumed only after ≥2 barriers, all waves park first ----
    const char* gb = (const char*)gbf + (size_t)b * 32768;
    {
        int o0 = tid * 16, o1 = (1024 + tid) * 16;
        uint4 q0 = *(const uint4*)(gb + o0);
        uint4 q1 = *(const uint4*)(gb + o1);
        *(uint4*)(Gs + (o0 ^ (((o0 >> 8) & 15) << 4))) = q0;
        *(uint4*)(Gs + (o1 ^ (((o1 >> 8) & 15) << 4))) = q1;
    }

    const int i_idx = whi * 16 + lr;              // this thread's vertex row (fixed)
    const float invd = invdeg[b * 128 + i_idx];

    // ---- v in registers, GEMM2 C-layout: (row d = wlo*128+mi*16+lq*4+r, col i = i_idx) ----
    float* vb = v_io + (size_t)b * 128 * 256;
    f32x4 vreg[8];
    #pragma unroll
    for (int mi = 0; mi < 8; ++mi)
        vreg[mi] = *(const f32x4*)(vb + (size_t)i_idx * 256 + wlo * 128 + mi * 16 + lq * 4);

    for (int layer = 0; layer < Lnum; ++layer) {
        const char* wh  = (const char*)wthi_all + (size_t)layer * 131072;
        const char* wl_ = (const char*)wtlo_all + (size_t)layer * 131072;
        const float* bias = b_all + layer * 256;

        __syncthreads();                 // prev layer's VP reads complete (VP aliases As)
        // ---- step 1: v regs -> As split [j=i][k=d] ----
        #pragma unroll
        for (int mi = 0; mi < 8; ++mi) {
            ushort4 h4, l4;
            split4(vreg[mi], h4, l4);
            int off = (i_idx * 512 + wlo * 256 + mi * 32 + lq * 8) ^ sw;
            *(ushort4*)(AsH + off) = h4;
            *(ushort4*)(AsL + off) = l4;
        }
        __syncthreads();

        // ---- GEMM1: D1[j][d] = v@W; A rows j = i_idx (16/wave), B = W^T global (128 d/wave) ----
        f32x4 z = {0.f, 0.f, 0.f, 0.f};
        f32x4 acc[8];
        #pragma unroll
        for (int bn = 0; bn < 8; ++bn) acc[bn] = z;

        #pragma unroll 2
        for (int kc = 0; kc < 8; ++kc) {
            int aoff = (i_idx * 512 + kc * 64 + lq * 16) ^ sw;
            short8 Ah = *(const short8*)(AsH + aoff);
            short8 Al = *(const short8*)(AsL + aoff);
            #pragma unroll
            for (int bn = 0; bn < 8; ++bn) {
                size_t woff = (size_t)(wlo * 128 + bn * 16 + lr) * 512 + kc * 64 + lq * 16;
                short8 Bh = *(const short8*)(wh + woff);
                short8 Bl = *(const short8*)(wl_ + woff);
                acc[bn] = __builtin_amdgcn_mfma_f32_16x16x32_bf16(Ah, Bh, acc[bn], 0, 0, 0);
                acc[bn] = __builtin_amdgcn_mfma_f32_16x16x32_bf16(Al, Bh, acc[bn], 0, 0, 0);
                acc[bn] = __builtin_amdgcn_mfma_f32_16x16x32_bf16(Ah, Bl, acc[bn], 0, 0, 0);
            }
        }
        __syncthreads();                 // As reads done; VP may overwrite

        // ---- epi 1: vp = acc + bias -> split -> VP [d][j] ----
        // acc C-layout: row j = whi*16 + lq*4 + r, col d = wlo*128 + bn*16 + lr
        #pragma unroll
        for (int bn = 0; bn < 8; ++bn) {
            int d = wlo * 128 + bn * 16 + lr;
            float bvv = bias[d];
            f32x4 t = acc[bn];
            t[0] += bvv; t[1] += bvv; t[2] += bvv; t[3] += bvv;
            ushort4 h4, l4;
            split4(t, h4, l4);
            int off = (d * 256 + (whi * 16 + lq * 4) * 2) ^ sw;
            *(ushort4*)(VPH + off) = h4;
            *(ushort4*)(VPL + off) = l4;
        }
        __syncthreads();

        // ---- GEMM2: D2[d][i] = sum_j vp[d][j] * Gp[i][j] (hi seg, then lo seg) ----
        f32x4 acc2[8];
        #pragma unroll
        for (int mi = 0; mi < 8; ++mi) acc2[mi] = z;

        short8 g[4];
        #pragma unroll
        for (int kc = 0; kc < 4; ++kc)
            g[kc] = *(const short8*)(Gs + ((i_idx * 256 + kc * 64 + lq * 16) ^ sw));

        #pragma unroll
        for (int s = 0; s < 2; ++s) {
            const char* Aseg = s ? VPL : VPH;
            #pragma unroll
            for (int kc = 0; kc < 4; ++kc) {
                #pragma unroll
                for (int mh = 0; mh < 2; ++mh) {        // 2 batches of 4: caps reg pressure
                    short8 Af[4];
                    #pragma unroll
                    for (int mi = 0; mi < 4; ++mi) {
                        int d = wlo * 128 + (mh * 4 + mi) * 16 + lr;
                        Af[mi] = *(const short8*)(Aseg + ((d * 256 + kc * 64 + lq * 16) ^ sw));
                    }
                    #pragma unroll
                    for (int mi = 0; mi < 4; ++mi)
                        acc2[mh * 4 + mi] = __builtin_amdgcn_mfma_f32_16x16x32_bf16(
                            Af[mi], g[kc], acc2[mh * 4 + mi], 0, 0, 0);
                }
            }
        }

        // ---- epi 2 (registers): v += relu(D2 * invdeg) ----
        #pragma unroll
        for (int mi = 0; mi < 8; ++mi)
            #pragma unroll
            for (int r = 0; r < 4; ++r)
                vreg[mi][r] += fmaxf(acc2[mi][r] * invd, 0.0f);
    }

    // ---- store v back ----
    #pragma unroll
    for (int mi = 0; mi < 8; ++mi)
        *(f32x4*)(vb + (size_t)i_idx * 256 + wlo * 128 + mi * 16 + lq * 4) = vreg[mi];
}

// ---------------- LayerNorm: read v fp32, write split h ----------------
__global__ __launch_bounds__(256) void ln_kernel(const float* __restrict__ v,
                                                 const float* __restrict__ g,
                                                 const float* __restrict__ beta,
                                                 u16* __restrict__ hhi,
                                                 u16* __restrict__ hlo) {
    __shared__ float sbuf[4];
    int row = blockIdx.x;
    int t = threadIdx.x;
    float x = v[(size_t)row * Hdim + t];
    float s = x;
    #pragma unroll
    for (int off = 32; off; off >>= 1) s += __shfl_down(s, off);
    int wid = t >> 6, lane = t & 63;
    if (lane == 0) sbuf[wid] = s;
    __syncthreads();
    float mu = (sbuf[0] + sbuf[1] + sbuf[2] + sbuf[3]) * (1.0f / Hdim);
    __syncthreads();
    float d = x - mu;
    float sq = d * d;
    #pragma unroll
    for (int off = 32; off; off >>= 1) sq += __shfl_down(sq, off);
    if (lane == 0) sbuf[wid] = sq;
    __syncthreads();
    float var = (sbuf[0] + sbuf[1] + sbuf[2] + sbuf[3]) * (1.0f / Hdim);
    float h = d * (1.0f / sqrtf(var + LN_EPS)) * g[t] + beta[t];
    size_t idx = (size_t)row * Hdim + t;
    u16 hb = f2bf(h);
    hhi[idx] = hb;
    hlo[idx] = f2bf(h - bf2f(hb));
}

// ---------------- fused final GEMM (direct staging + swizzle): part[m][nb] ----------------
__global__ __launch_bounds__(256) void gemm_fin_mfma(const u16* __restrict__ hhi,
                                                     const u16* __restrict__ hlo,
                                                     const u16* __restrict__ wfhi,
                                                     const u16* __restrict__ wflo,
                                                     const float* __restrict__ bfin,
                                                     const float* __restrict__ wout,
                                                     float* __restrict__ part) {
    __shared__ char smem[24576];
    char* As = smem;                 // 16384 (rows 128B)
    char* Bs = smem + 16384;         // 8192  (rows 128B)
    int tid = threadIdx.x, l = tid & 63, w = tid >> 6, wr = w >> 1, wc = w & 1;
    int m0 = blockIdx.x * 128, n0 = blockIdx.y * 64;
    const int lr = l & 15, lq = l >> 4, lkb = lq * 16;
    const int sw = (lr & 7) << 4;
    const char* segA[3] = {(const char*)hhi, (const char*)hlo, (const char*)hhi};
    const char* segB[3] = {(const char*)wfhi, (const char*)wfhi, (const char*)wflo};
    f32x4 z = {0.f, 0.f, 0.f, 0.f};
    f32x4 acc[4][2];
    #pragma unroll
    for (int mi = 0; mi < 4; ++mi) { acc[mi][0] = z; acc[mi][1] = z; }

    for (int q = 0; q < 12; ++q) {
        const char* A = segA[q >> 2] + (size_t)m0 * 512 + (q & 3) * 128;
        const char* B = segB[q >> 2] + (size_t)n0 * 512 + (q & 3) * 128;
        #pragma unroll
        for (int u = 0; u < 4; ++u) {
            int off = (u * 256 + tid) * 16;
            int row = off >> 7;
            *(uint4*)(As + (off ^ ((row & 7) << 4))) =
                *(const uint4*)(A + (size_t)row * 512 + (off & 127));
        }
        #pragma unroll
        for (int u = 0; u < 2; ++u) {
            int off = (u * 256 + tid) * 16;
            int row = off >> 7;
            *(uint4*)(Bs + (off ^ ((row & 7) << 4))) =
                *(const uint4*)(B + (size_t)row * 512 + (off & 127));
        }
        __syncthreads();
        #pragma unroll
        for (int kk = 0; kk < 2; ++kk) {
            short8 a[4], b2[2];
            #pragma unroll
            for (int mi = 0; mi < 4; ++mi)
                a[mi] = *(const short8*)(As + (((wr * 64 + mi * 16 + lr) * 128 + kk * 64 + lkb) ^ sw));
            #pragma unroll
            for (int ni = 0; ni < 2; ++ni)
                b2[ni] = *(const short8*)(Bs + (((wc * 32 + ni * 16 + lr) * 128 + kk * 64 + lkb) ^ sw));
            #pragma unroll
            for (int mi = 0; mi < 4; ++mi)
                #pragma unroll
                for (int ni = 0; ni < 2; ++ni)
                    acc[mi][ni] = __builtin_amdgcn_mfma_f32_16x16x32_bf16(a[mi], b2[ni],
                                                                         acc[mi][ni], 0, 0, 0);
        }
        __syncthreads();
    }
    float rs[4][4];
    #pragma unroll
    for (int mi = 0; mi < 4; ++mi)
        #pragma unroll
        for (int r = 0; r < 4; ++r) rs[mi][r] = 0.0f;
    #pragma unroll
    for (int ni = 0; ni < 2; ++ni) {
        int n = n0 + wc * 32 + ni * 16 + lr;
        float bvv = bfin[n], wo = wout[n];
        #pragma unroll
        for (int mi = 0; mi < 4; ++mi)
            #pragma unroll
            for (int r = 0; r < 4; ++r)
                rs[mi][r] += fmaxf(acc[mi][ni][r] + bvv, 0.0f) * wo;
    }
    float* red = (float*)smem;          // [128][33] floats; loop ended with barrier
    #pragma unroll
    for (int mi = 0; mi < 4; ++mi)
        #pragma unroll
        for (int r = 0; r < 4; ++r) {
            int row = wr * 64 + mi * 16 + lq * 4 + r;
            red[row * 33 + wc * 16 + lr] = rs[mi][r];
        }
    __syncthreads();
    if (tid < 128) {
        float s = 0.0f;
        #pragma unroll
        for (int c = 0; c < 32; ++c) s += red[tid * 33 + c];
        part[(size_t)(m0 + tid) * 16 + blockIdx.y] = s;
    }
}

// ---------------- final reduce ----------------
__global__ __launch_bounds__(256) void final_kernel(const float* __restrict__ part,
                                                    const float* __restrict__ bo,
                                                    float* __restrict__ out) {
    int i = blockIdx.x * 256 + threadIdx.x;
    float s = bo[0];
    #pragma unroll
    for (int t = 0; t < 16; ++t) s += part[(size_t)i * 16 + t];
    out[i] = s;
}

extern "C" void kernel_launch(void* const* d_in, const int* in_sizes, int n_in,
                              void* d_out, int out_size, void* d_ws, size_t ws_size,
                              hipStream_t stream) {
    const float* x        = (const float*)d_in[0];
    const float* G        = (const float*)d_in[1];
    const float* W_feat   = (const float*)d_in[2];
    const float* b_feat   = (const float*)d_in[3];
    const float* W_layers = (const float*)d_in[4];
    const float* b_layers = (const float*)d_in[5];
    const float* ln_g     = (const float*)d_in[6];
    const float* ln_b     = (const float*)d_in[7];
    const float* W_fin    = (const float*)d_in[8];
    const float* b_fin    = (const float*)d_in[9];
    const float* W_out    = (const float*)d_in[10];
    const float* b_out    = (const float*)d_in[11];
    float* out = (float*)d_out;

    const int M = Bsz * Vn;                          // 16384
    char* ws = (char*)d_ws;
    float* v0     = (float*)ws;                      ws += (size_t)M * Hdim * 4;     // 16 MB
    u16*   gbf    = (u16*)ws;                        ws += (size_t)Bsz * Vn * Vn * 2;   // 4 MB
    u16*   wthi   = (u16*)ws;                        ws += (size_t)Lnum * Hdim * Hdim * 2; // 4 MB
    u16*   wtlo   = (u16*)ws;                        ws += (size_t)Lnum * Hdim * Hdim * 2; // 4 MB
    u16*   wfhi   = (u16*)ws;                        ws += (size_t)FLdim * Hdim * 2;  // 0.5 MB
    u16*   wflo   = (u16*)ws;                        ws += (size_t)FLdim * Hdim * 2;  // 0.5 MB
    float* nrow   = (float*)ws;                      ws += (size_t)M * 4;
    float* invdeg = (float*)ws;                      ws += (size_t)M * 4;
    float* part   = (float*)ws;                      ws += (size_t)M * 16 * 4;        // 1 MB
    u16*   hh     = (u16*)ws;                        ws += (size_t)M * Hdim * 2;      // 8 MB
    u16*   hl     = (u16*)ws;                        ws += (size_t)M * Hdim * 2;      // 8 MB

    hipFuncSetAttribute((const void*)layers_all,
                        hipFuncAttributeMaxDynamicSharedMemorySize, 163840);

    rowsum_kernel<<<M / 4, 256, 0, stream>>>(G, nrow, invdeg);
    gbf_kernel<<<(Bsz * Vn * 16) / 256, 256, 0, stream>>>(G, nrow, gbf);
    tsplit_kernel<<<dim3(4, 4, Lnum), 256, 0, stream>>>(W_layers, wthi, wtlo, Hdim, Hdim);
    tsplit_kernel<<<dim3(4, 16, 1), 256, 0, stream>>>(W_fin, wfhi, wflo, FLdim, Hdim);
    feat_kernel<<<M, 256, 0, stream>>>(x, W_feat, b_feat, v0);

    layers_all<<<Bsz, 1024, 163840, stream>>>(v0, wthi, wtlo, b_layers, gbf, invdeg);

    ln_kernel<<<M, 256, 0, stream>>>(v0, ln_g, ln_b, hh, hl);
    gemm_fin_mfma<<<dim3(M / 128, FLdim / 64), 256, 0, stream>>>(
        hh, hl, wfhi, wflo, b_fin, W_out, part);
    final_kernel<<<M / 256, 256, 0, stream>>>(part, b_out, out);
}

// Round 12
// 1783.100 us; speedup vs baseline: 1.5075x; 1.5075x over previous
//
#include <hip/hip_runtime.h>

// VonMisesNet: B=128, V=128, F=40, H=256, L=32, FL=1024, OUT=1
#define Bsz 128
#define Vn  128
#define Fdim 40
#define Hdim 256
#define Lnum 32
#define FLdim 1024
#define LN_EPS 1e-5f

typedef unsigned short u16;
typedef __attribute__((ext_vector_type(8))) short short8;
typedef __attribute__((ext_vector_type(4))) float f32x4;

__device__ __forceinline__ u16 f2bf(float f) {
    unsigned u = __float_as_uint(f);
    u += 0x7fff + ((u >> 16) & 1);          // round-to-nearest-even
    return (u16)(u >> 16);
}
__device__ __forceinline__ float bf2f(u16 s) {
    return __uint_as_float((unsigned)s << 16);
}

__device__ __forceinline__ void split4(const f32x4& f, ushort4& h4, ushort4& l4) {
    u16 h0 = f2bf(f[0]), h1 = f2bf(f[1]), h2 = f2bf(f[2]), h3 = f2bf(f[3]);
    h4.x = h0; h4.y = h1; h4.z = h2; h4.w = h3;
    l4.x = f2bf(f[0] - bf2f(h0));
    l4.y = f2bf(f[1] - bf2f(h1));
    l4.z = f2bf(f[2] - bf2f(h2));
    l4.w = f2bf(f[3] - bf2f(h3));
}

__device__ __forceinline__ void splitpack(const float4& x, const float4& y,
                                          uint4& h, uint4& lo) {
    float f[8] = {x.x, x.y, x.z, x.w, y.x, y.y, y.z, y.w};
    u16 hh[8], ll[8];
    #pragma unroll
    for (int e = 0; e < 8; ++e) {
        hh[e] = f2bf(f[e]);
        ll[e] = f2bf(f[e] - bf2f(hh[e]));
    }
    h.x  = (unsigned)hh[0] | ((unsigned)hh[1] << 16);
    h.y  = (unsigned)hh[2] | ((unsigned)hh[3] << 16);
    h.z  = (unsigned)hh[4] | ((unsigned)hh[5] << 16);
    h.w  = (unsigned)hh[6] | ((unsigned)hh[7] << 16);
    lo.x = (unsigned)ll[0] | ((unsigned)ll[1] << 16);
    lo.y = (unsigned)ll[2] | ((unsigned)ll[3] << 16);
    lo.z = (unsigned)ll[4] | ((unsigned)ll[5] << 16);
    lo.w = (unsigned)ll[6] | ((unsigned)ll[7] << 16);
}

// ---------------- rowsum: n[m] = sum_j G[m,j]; invdeg = 1/(n + (n==0)) ----------------
__global__ __launch_bounds__(256) void rowsum_kernel(const float* __restrict__ G,
                                                     float* __restrict__ nrow,
                                                     float* __restrict__ invdeg) {
    int row = blockIdx.x * 4 + (threadIdx.x >> 6);
    int lane = threadIdx.x & 63;
    const float* g = G + (size_t)row * Vn;
    float s = g[lane] + g[lane + 64];
    #pragma unroll
    for (int off = 32; off; off >>= 1) s += __shfl_down(s, off);
    if (lane == 0) {
        nrow[row] = s;
        invdeg[row] = 1.0f / (s + (s == 0.0f ? 1.0f : 0.0f));
    }
}

// ---------------- Gbf[b][i][j] = bf16(G + diag(n)) (exact: 0/1/int) ----------------
__global__ __launch_bounds__(256) void gbf_kernel(const float* __restrict__ G,
                                                  const float* __restrict__ nrow,
                                                  u16* __restrict__ gbf) {
    int gid = blockIdx.x * 256 + threadIdx.x;      // handles 8 j's
    int j8 = gid & 15;
    int m  = gid >> 4;                             // b*128 + i
    int i  = m & 127;
    const float* src = G + (size_t)m * Vn + j8 * 8;
    float4 g0 = *(const float4*)src;
    float4 g1 = *(const float4*)(src + 4);
    float nb = nrow[m];
    float ge[8] = {g0.x, g0.y, g0.z, g0.w, g1.x, g1.y, g1.z, g1.w};
    u16 us[8];
    #pragma unroll
    for (int e = 0; e < 8; ++e) {
        float val = ge[e] + ((j8 * 8 + e) == i ? nb : 0.0f);
        us[e] = f2bf(val);
    }
    uint4 pack;
    pack.x = (unsigned)us[0] | ((unsigned)us[1] << 16);
    pack.y = (unsigned)us[2] | ((unsigned)us[3] << 16);
    pack.z = (unsigned)us[4] | ((unsigned)us[5] << 16);
    pack.w = (unsigned)us[6] | ((unsigned)us[7] << 16);
    *(uint4*)(gbf + (size_t)m * Vn + j8 * 8) = pack;
}

// ------------- transpose+split: src[K][N] f32 -> hi/lo[N][K] bf16 (per blockIdx.z mat) -------------
__global__ __launch_bounds__(256) void tsplit_kernel(const float* __restrict__ src,
                                                     u16* __restrict__ hi, u16* __restrict__ lo,
                                                     int N, int K) {
    __shared__ float tl[64][65];
    size_t mat = (size_t)blockIdx.z * K * N;
    int k0 = blockIdx.x * 64, n0 = blockIdx.y * 64;
    int t = threadIdx.x, c = t & 63, r4 = t >> 6;
    #pragma unroll
    for (int i = 0; i < 16; ++i) {
        int r = i * 4 + r4;
        tl[r][c] = src[mat + (size_t)(k0 + r) * N + n0 + c];
    }
    __syncthreads();
    #pragma unroll
    for (int i = 0; i < 16; ++i) {
        int nr = i * 4 + r4;
        float val = tl[c][nr];
        u16 h = f2bf(val);
        size_t idx = mat + (size_t)(n0 + nr) * K + k0 + c;
        hi[idx] = h;
        lo[idx] = f2bf(val - bf2f(h));
    }
}

// ---------------- feat: v = x@W_feat + b_feat (fp32 master only) ----------------
__global__ __launch_bounds__(256) void feat_kernel(const float* __restrict__ x,
                                                   const float* __restrict__ Wf,
                                                   const float* __restrict__ bf,
                                                   float* __restrict__ v) {
    __shared__ float xs[Fdim];
    int row = blockIdx.x;
    int h = threadIdx.x;
    if (h < Fdim) xs[h] = x[(size_t)row * Fdim + h];
    __syncthreads();
    float acc = bf[h];
    #pragma unroll 8
    for (int f = 0; f < Fdim; ++f) acc += xs[f] * Wf[f * Hdim + h];
    v[(size_t)row * Hdim + h] = acc;
}

// ======== merged layer: one block per batch (grid 128, 512 thr), sequential d-halves ========
// Per dh: stage v->As (split, k-chunks of 64) -> GEMM1 (W from global) -> VP -> GEMM2 (G in regs)
//   -> epi writes v_out half. v staged once from HBM (dh=1 restage is L2-hot).
// LDS 96K: AsH 16K @0 [128 j][128B], AsL 16K @16K, VPH 32K @32K [128 d][256B], VPL 32K @64K.
// Swizzles: As rows 128B -> ^((row&7)<<4); VP rows 256B -> ^((row&15)<<4) == ^(lr<<4).
// Register budget: acc 8 frags (32) + gfr 8 (32) + staging/temps ~40 => ~110 <= 128 (R8-R11 lesson).
__global__ __launch_bounds__(512) void layer_merged(const float* __restrict__ v_in,
                                                    float* __restrict__ v_out,
                                                    const u16* __restrict__ wthi,
                                                    const u16* __restrict__ wtlo,
                                                    const float* __restrict__ bias,
                                                    const u16* __restrict__ gbf,
                                                    const float* __restrict__ invdeg) {
    extern __shared__ char smem[];
    char* AsH = smem;                 // 16K
    char* AsL = smem + 16384;         // 16K
    char* VPH = smem + 32768;         // 32K
    char* VPL = smem + 65536;         // 32K

    const int tid = threadIdx.x, l = tid & 63, w = tid >> 6;
    const int whi = w >> 1, wlo = w & 1;   // GEMM1: whi=j-group(4x32), wlo=d-group(2x64)
                                           // GEMM2: whi=i-group(4x32), wlo=d-group(2x64)
    const int b = blockIdx.x;
    const int lr = l & 15, lq = l >> 4;
    const int swv = lr << 4;               // VP swizzle (rows ≡ lr mod 16)
    const int swa = (lr & 7) << 4;         // As swizzle (rows ≡ lr mod 16, 8-row stripes)

    // ---- G fragments in registers (B-operand of GEMM2): rows i = whi*32+ni*16+lr ----
    const char* gb = (const char*)gbf + (size_t)b * 32768;
    short8 gfr[2][4];
    #pragma unroll
    for (int ni = 0; ni < 2; ++ni)
        #pragma unroll
        for (int kc = 0; kc < 4; ++kc)
            gfr[ni][kc] = *(const short8*)(gb + (size_t)(whi * 32 + ni * 16 + lr) * 256 + kc * 64 + lq * 16);

    float invd[2];
    #pragma unroll
    for (int ni = 0; ni < 2; ++ni) invd[ni] = invdeg[b * 128 + whi * 32 + ni * 16 + lr];

    const float* vb = v_in + (size_t)b * 128 * 256;
    float* vo = v_out + (size_t)b * 128 * 256;

    // staging geometry: thread covers row j = tid>>2, 16 floats at col (tid&3)*16
    const int sj = tid >> 2, scg = tid & 3;
    const int sbase = (sj * 128 + scg * 32);
    const int sswz = (sj & 7) << 4;

    f32x4 z = {0.f, 0.f, 0.f, 0.f};

    for (int dh = 0; dh < 2; ++dh) {
        const char* wh  = (const char*)wthi + (size_t)dh * 128 * 512;
        const char* wl_ = (const char*)wtlo + (size_t)dh * 128 * 512;

        // ---- GEMM1: D1[j][d] = v @ W[:, dh-half], split-bf16, K=256 in 4 chunks of 64 ----
        f32x4 acc1[2][4];                 // [am j-frag][bn d-frag]
        #pragma unroll
        for (int am = 0; am < 2; ++am)
            #pragma unroll
            for (int bn = 0; bn < 4; ++bn) acc1[am][bn] = z;

        for (int c = 0; c < 4; ++c) {
            __syncthreads();              // As (and, at c=0, VP of prev dh) consumers done
            {
                const float* p = vb + (size_t)sj * 256 + c * 64 + scg * 16;
                float4 f0 = *(const float4*)p;
                float4 f1 = *(const float4*)(p + 4);
                float4 f2 = *(const float4*)(p + 8);
                float4 f3 = *(const float4*)(p + 12);
                uint4 h, lo;
                splitpack(f0, f1, h, lo);
                *(uint4*)(AsH + ((sbase + 0) ^ sswz)) = h;
                *(uint4*)(AsL + ((sbase + 0) ^ sswz)) = lo;
                splitpack(f2, f3, h, lo);
                *(uint4*)(AsH + ((sbase + 16) ^ sswz)) = h;
                *(uint4*)(AsL + ((sbase + 16) ^ sswz)) = lo;
            }
            __syncthreads();
            #pragma unroll
            for (int kk = 0; kk < 2; ++kk) {
                short8 Ah[2], Al[2];
                #pragma unroll
                for (int am = 0; am < 2; ++am) {
                    int off = ((whi * 32 + am * 16 + lr) * 128 + kk * 64 + lq * 16) ^ swa;
                    Ah[am] = *(const short8*)(AsH + off);
                    Al[am] = *(const short8*)(AsL + off);
                }
                #pragma unroll
                for (int bn = 0; bn < 4; ++bn) {
                    size_t woff = (size_t)(wlo * 64 + bn * 16 + lr) * 512 + (c * 2 + kk) * 64 + lq * 16;
                    short8 Bh = *(const short8*)(wh + woff);
                    short8 Bl = *(const short8*)(wl_ + woff);
                    #pragma unroll
                    for (int am = 0; am < 2; ++am) {
                        acc1[am][bn] = __builtin_amdgcn_mfma_f32_16x16x32_bf16(Ah[am], Bh, acc1[am][bn], 0, 0, 0);
                        acc1[am][bn] = __builtin_amdgcn_mfma_f32_16x16x32_bf16(Al[am], Bh, acc1[am][bn], 0, 0, 0);
                        acc1[am][bn] = __builtin_amdgcn_mfma_f32_16x16x32_bf16(Ah[am], Bl, acc1[am][bn], 0, 0, 0);
                    }
                }
            }
        }
        __syncthreads();                  // last As reads done

        // ---- epi1: vp = acc1 + bias -> split -> VP [d_local][j] ----
        // acc1 C-layout: row j = whi*32 + am*16 + lq*4 + r, col d_local = wlo*64 + bn*16 + lr
        #pragma unroll
        for (int am = 0; am < 2; ++am)
            #pragma unroll
            for (int bn = 0; bn < 4; ++bn) {
                int dl = wlo * 64 + bn * 16 + lr;
                float bvv = bias[dh * 128 + dl];
                int j0 = whi * 32 + am * 16 + lq * 4;
                f32x4 t = acc1[am][bn];
                t[0] += bvv; t[1] += bvv; t[2] += bvv; t[3] += bvv;
                ushort4 h4, l4;
                split4(t, h4, l4);
                int off = (dl * 256 + j0 * 2) ^ swv;
                *(ushort4*)(VPH + off) = h4;
                *(ushort4*)(VPL + off) = l4;
            }
        __syncthreads();

        // ---- GEMM2: D2[d][i] = sum_j vp[d][j] * Gp[i][j] (hi seg then lo seg) ----
        f32x4 acc2[4][2];                 // [mi d-frag][ni i-frag]
        #pragma unroll
        for (int mi = 0; mi < 4; ++mi) { acc2[mi][0] = z; acc2[mi][1] = z; }

        #pragma unroll
        for (int s = 0; s < 2; ++s) {
            const char* Aseg = s ? VPL : VPH;
            #pragma unroll
            for (int kc = 0; kc < 4; ++kc) {
                short8 Af[4];
                #pragma unroll
                for (int mi = 0; mi < 4; ++mi) {
                    int off = ((wlo * 64 + mi * 16 + lr) * 256 + kc * 64 + lq * 16) ^ swv;
                    Af[mi] = *(const short8*)(Aseg + off);
                }
                #pragma unroll
                for (int mi = 0; mi < 4; ++mi)
                    #pragma unroll
                    for (int ni = 0; ni < 2; ++ni)
                        acc2[mi][ni] = __builtin_amdgcn_mfma_f32_16x16x32_bf16(
                            Af[mi], gfr[ni][kc], acc2[mi][ni], 0, 0, 0);
            }
        }

        // ---- epi2: v_out[i][d] = v_in[i][d] + relu(D2 * invdeg)  (v_in L2-hot) ----
        // acc2 C-layout: row d_local = wlo*64 + mi*16 + lq*4 + r, col i = whi*32 + ni*16 + lr
        #pragma unroll
        for (int mi = 0; mi < 4; ++mi)
            #pragma unroll
            for (int ni = 0; ni < 2; ++ni) {
                int i = whi * 32 + ni * 16 + lr;
                int d0 = dh * 128 + wlo * 64 + mi * 16 + lq * 4;
                float4 c4 = *(const float4*)(vb + (size_t)i * 256 + d0);
                float4 o;
                o.x = c4.x + fmaxf(acc2[mi][ni][0] * invd[ni], 0.0f);
                o.y = c4.y + fmaxf(acc2[mi][ni][1] * invd[ni], 0.0f);
                o.z = c4.z + fmaxf(acc2[mi][ni][2] * invd[ni], 0.0f);
                o.w = c4.w + fmaxf(acc2[mi][ni][3] * invd[ni], 0.0f);
                *(float4*)(vo + (size_t)i * 256 + d0) = o;
            }
    }
}

// ---------------- LayerNorm: read v fp32, write split h ----------------
__global__ __launch_bounds__(256) void ln_kernel(const float* __restrict__ v,
                                                 const float* __restrict__ g,
                                                 const float* __restrict__ beta,
                                                 u16* __restrict__ hhi,
                                                 u16* __restrict__ hlo) {
    __shared__ float sbuf[4];
    int row = blockIdx.x;
    int t = threadIdx.x;
    float x = v[(size_t)row * Hdim + t];
    float s = x;
    #pragma unroll
    for (int off = 32; off; off >>= 1) s += __shfl_down(s, off);
    int wid = t >> 6, lane = t & 63;
    if (lane == 0) sbuf[wid] = s;
    __syncthreads();
    float mu = (sbuf[0] + sbuf[1] + sbuf[2] + sbuf[3]) * (1.0f / Hdim);
    __syncthreads();
    float d = x - mu;
    float sq = d * d;
    #pragma unroll
    for (int off = 32; off; off >>= 1) sq += __shfl_down(sq, off);
    if (lane == 0) sbuf[wid] = sq;
    __syncthreads();
    float var = (sbuf[0] + sbuf[1] + sbuf[2] + sbuf[3]) * (1.0f / Hdim);
    float h = d * (1.0f / sqrtf(var + LN_EPS)) * g[t] + beta[t];
    size_t idx = (size_t)row * Hdim + t;
    u16 hb = f2bf(h);
    hhi[idx] = hb;
    hlo[idx] = f2bf(h - bf2f(hb));
}

// ---------------- fused final GEMM (direct staging + swizzle): part[m][nb] ----------------
__global__ __launch_bounds__(256) void gemm_fin_mfma(const u16* __restrict__ hhi,
                                                     const u16* __restrict__ hlo,
                                                     const u16* __restrict__ wfhi,
                                                     const u16* __restrict__ wflo,
                                                     const float* __restrict__ bfin,
                                                     const float* __restrict__ wout,
                                                     float* __restrict__ part) {
    __shared__ char smem[24576];
    char* As = smem;                 // 16384 (rows 128B)
    char* Bs = smem + 16384;         // 8192  (rows 128B)
    int tid = threadIdx.x, l = tid & 63, w = tid >> 6, wr = w >> 1, wc = w & 1;
    int m0 = blockIdx.x * 128, n0 = blockIdx.y * 64;
    const int lr = l & 15, lq = l >> 4, lkb = lq * 16;
    const int sw = (lr & 7) << 4;
    const char* segA[3] = {(const char*)hhi, (const char*)hlo, (const char*)hhi};
    const char* segB[3] = {(const char*)wfhi, (const char*)wfhi, (const char*)wflo};
    f32x4 z = {0.f, 0.f, 0.f, 0.f};
    f32x4 acc[4][2];
    #pragma unroll
    for (int mi = 0; mi < 4; ++mi) { acc[mi][0] = z; acc[mi][1] = z; }

    for (int q = 0; q < 12; ++q) {
        const char* A = segA[q >> 2] + (size_t)m0 * 512 + (q & 3) * 128;
        const char* B = segB[q >> 2] + (size_t)n0 * 512 + (q & 3) * 128;
        #pragma unroll
        for (int u = 0; u < 4; ++u) {
            int off = (u * 256 + tid) * 16;
            int row = off >> 7;
            *(uint4*)(As + (off ^ ((row & 7) << 4))) =
                *(const uint4*)(A + (size_t)row * 512 + (off & 127));
        }
        #pragma unroll
        for (int u = 0; u < 2; ++u) {
            int off = (u * 256 + tid) * 16;
            int row = off >> 7;
            *(uint4*)(Bs + (off ^ ((row & 7) << 4))) =
                *(const uint4*)(B + (size_t)row * 512 + (off & 127));
        }
        __syncthreads();
        #pragma unroll
        for (int kk = 0; kk < 2; ++kk) {
            short8 a[4], b2[2];
            #pragma unroll
            for (int mi = 0; mi < 4; ++mi)
                a[mi] = *(const short8*)(As + (((wr * 64 + mi * 16 + lr) * 128 + kk * 64 + lkb) ^ sw));
            #pragma unroll
            for (int ni = 0; ni < 2; ++ni)
                b2[ni] = *(const short8*)(Bs + (((wc * 32 + ni * 16 + lr) * 128 + kk * 64 + lkb) ^ sw));
            #pragma unroll
            for (int mi = 0; mi < 4; ++mi)
                #pragma unroll
                for (int ni = 0; ni < 2; ++ni)
                    acc[mi][ni] = __builtin_amdgcn_mfma_f32_16x16x32_bf16(a[mi], b2[ni],
                                                                         acc[mi][ni], 0, 0, 0);
        }
        __syncthreads();
    }
    float rs[4][4];
    #pragma unroll
    for (int mi = 0; mi < 4; ++mi)
        #pragma unroll
        for (int r = 0; r < 4; ++r) rs[mi][r] = 0.0f;
    #pragma unroll
    for (int ni = 0; ni < 2; ++ni) {
        int n = n0 + wc * 32 + ni * 16 + lr;
        float bvv = bfin[n], wo = wout[n];
        #pragma unroll
        for (int mi = 0; mi < 4; ++mi)
            #pragma unroll
            for (int r = 0; r < 4; ++r)
                rs[mi][r] += fmaxf(acc[mi][ni][r] + bvv, 0.0f) * wo;
    }
    float* red = (float*)smem;          // [128][33] floats; loop ended with barrier
    #pragma unroll
    for (int mi = 0; mi < 4; ++mi)
        #pragma unroll
        for (int r = 0; r < 4; ++r) {
            int row = wr * 64 + mi * 16 + lq * 4 + r;
            red[row * 33 + wc * 16 + lr] = rs[mi][r];
        }
    __syncthreads();
    if (tid < 128) {
        float s = 0.0f;
        #pragma unroll
        for (int c = 0; c < 32; ++c) s += red[tid * 33 + c];
        part[(size_t)(m0 + tid) * 16 + blockIdx.y] = s;
    }
}

// ---------------- final reduce ----------------
__global__ __launch_bounds__(256) void final_kernel(const float* __restrict__ part,
                                                    const float* __restrict__ bo,
                                                    float* __restrict__ out) {
    int i = blockIdx.x * 256 + threadIdx.x;
    float s = bo[0];
    #pragma unroll
    for (int t = 0; t < 16; ++t) s += part[(size_t)i * 16 + t];
    out[i] = s;
}

extern "C" void kernel_launch(void* const* d_in, const int* in_sizes, int n_in,
                              void* d_out, int out_size, void* d_ws, size_t ws_size,
                              hipStream_t stream) {
    const float* x        = (const float*)d_in[0];
    const float* G        = (const float*)d_in[1];
    const float* W_feat   = (const float*)d_in[2];
    const float* b_feat   = (const float*)d_in[3];
    const float* W_layers = (const float*)d_in[4];
    const float* b_layers = (const float*)d_in[5];
    const float* ln_g     = (const float*)d_in[6];
    const float* ln_b     = (const float*)d_in[7];
    const float* W_fin    = (const float*)d_in[8];
    const float* b_fin    = (const float*)d_in[9];
    const float* W_out    = (const float*)d_in[10];
    const float* b_out    = (const float*)d_in[11];
    float* out = (float*)d_out;

    const int M = Bsz * Vn;                          // 16384
    char* ws = (char*)d_ws;
    float* v0     = (float*)ws;                      ws += (size_t)M * Hdim * 4;     // 16 MB
    float* v1     = (float*)ws;                      ws += (size_t)M * Hdim * 4;     // 16 MB
    u16*   gbf    = (u16*)ws;                        ws += (size_t)Bsz * Vn * Vn * 2;   // 4 MB
    u16*   wthi   = (u16*)ws;                        ws += (size_t)Lnum * Hdim * Hdim * 2; // 4 MB
    u16*   wtlo   = (u16*)ws;                        ws += (size_t)Lnum * Hdim * Hdim * 2; // 4 MB
    u16*   wfhi   = (u16*)ws;                        ws += (size_t)FLdim * Hdim * 2;  // 0.5 MB
    u16*   wflo   = (u16*)ws;                        ws += (size_t)FLdim * Hdim * 2;  // 0.5 MB
    float* nrow   = (float*)ws;                      ws += (size_t)M * 4;
    float* invdeg = (float*)ws;                      ws += (size_t)M * 4;
    float* part   = (float*)ws;                      ws += (size_t)M * 16 * 4;        // 1 MB

    // h splits alias v1 (dead after the layer loop: 32 layers end in v0)
    u16* hh = (u16*)v1;
    u16* hl = hh + (size_t)M * Hdim;

    float* vv[2] = {v0, v1};

    hipFuncSetAttribute((const void*)layer_merged,
                        hipFuncAttributeMaxDynamicSharedMemorySize, 98304);

    rowsum_kernel<<<M / 4, 256, 0, stream>>>(G, nrow, invdeg);
    gbf_kernel<<<(Bsz * Vn * 16) / 256, 256, 0, stream>>>(G, nrow, gbf);
    tsplit_kernel<<<dim3(4, 4, Lnum), 256, 0, stream>>>(W_layers, wthi, wtlo, Hdim, Hdim);
    tsplit_kernel<<<dim3(4, 16, 1), 256, 0, stream>>>(W_fin, wfhi, wflo, FLdim, Hdim);
    feat_kernel<<<M, 256, 0, stream>>>(x, W_feat, b_feat, v0);

    for (int l = 0; l < Lnum; ++l) {
        int in = l & 1;                  // l=0 reads v0 writes v1; alternate
        layer_merged<<<Bsz, 512, 98304, stream>>>(
            vv[in], vv[in ^ 1],
            wthi + (size_t)l * Hdim * Hdim, wtlo + (size_t)l * Hdim * Hdim,
            b_layers + (size_t)l * Hdim,
            gbf, invdeg);
    }

    ln_kernel<<<M, 256, 0, stream>>>(v0, ln_g, ln_b, hh, hl);
    gemm_fin_mfma<<<dim3(M / 128, FLdim / 64), 256, 0, stream>>>(
        hh, hl, wfhi, wflo, b_fin, W_out, part);
    final_kernel<<<M / 256, 256, 0, stream>>>(part, b_out, out);
}

// Round 13
// 1015.462 us; speedup vs baseline: 2.6470x; 1.7559x over previous
//
#include <hip/hip_runtime.h>

// VonMisesNet: B=128, V=128, F=40, H=256, L=32, FL=1024, OUT=1
#define Bsz 128
#define Vn  128
#define Fdim 40
#define Hdim 256
#define Lnum 32
#define FLdim 1024
#define LN_EPS 1e-5f

typedef unsigned short u16;
typedef __attribute__((ext_vector_type(8))) short short8;
typedef __attribute__((ext_vector_type(4))) float f32x4;

__device__ __forceinline__ u16 f2bf(float f) {
    unsigned u = __float_as_uint(f);
    u += 0x7fff + ((u >> 16) & 1);          // round-to-nearest-even
    return (u16)(u >> 16);
}
__device__ __forceinline__ float bf2f(u16 s) {
    return __uint_as_float((unsigned)s << 16);
}

__device__ __forceinline__ void split4(const f32x4& f, ushort4& h4, ushort4& l4) {
    u16 h0 = f2bf(f[0]), h1 = f2bf(f[1]), h2 = f2bf(f[2]), h3 = f2bf(f[3]);
    h4.x = h0; h4.y = h1; h4.z = h2; h4.w = h3;
    l4.x = f2bf(f[0] - bf2f(h0));
    l4.y = f2bf(f[1] - bf2f(h1));
    l4.z = f2bf(f[2] - bf2f(h2));
    l4.w = f2bf(f[3] - bf2f(h3));
}

__device__ __forceinline__ void splitpack(const float4& x, const float4& y,
                                          uint4& h, uint4& lo) {
    float f[8] = {x.x, x.y, x.z, x.w, y.x, y.y, y.z, y.w};
    u16 hh[8], ll[8];
    #pragma unroll
    for (int e = 0; e < 8; ++e) {
        hh[e] = f2bf(f[e]);
        ll[e] = f2bf(f[e] - bf2f(hh[e]));
    }
    h.x  = (unsigned)hh[0] | ((unsigned)hh[1] << 16);
    h.y  = (unsigned)hh[2] | ((unsigned)hh[3] << 16);
    h.z  = (unsigned)hh[4] | ((unsigned)hh[5] << 16);
    h.w  = (unsigned)hh[6] | ((unsigned)hh[7] << 16);
    lo.x = (unsigned)ll[0] | ((unsigned)ll[1] << 16);
    lo.y = (unsigned)ll[2] | ((unsigned)ll[3] << 16);
    lo.z = (unsigned)ll[4] | ((unsigned)ll[5] << 16);
    lo.w = (unsigned)ll[6] | ((unsigned)ll[7] << 16);
}

// ---------------- rowsum: n[m] = sum_j G[m,j]; invdeg = 1/(n + (n==0)) ----------------
__global__ __launch_bounds__(256) void rowsum_kernel(const float* __restrict__ G,
                                                     float* __restrict__ nrow,
                                                     float* __restrict__ invdeg) {
    int row = blockIdx.x * 4 + (threadIdx.x >> 6);
    int lane = threadIdx.x & 63;
    const float* g = G + (size_t)row * Vn;
    float s = g[lane] + g[lane + 64];
    #pragma unroll
    for (int off = 32; off; off >>= 1) s += __shfl_down(s, off);
    if (lane == 0) {
        nrow[row] = s;
        invdeg[row] = 1.0f / (s + (s == 0.0f ? 1.0f : 0.0f));
    }
}

// ---------------- Gbf[b][i][j] = bf16(G + diag(n)) (exact: 0/1/int) ----------------
__global__ __launch_bounds__(256) void gbf_kernel(const float* __restrict__ G,
                                                  const float* __restrict__ nrow,
                                                  u16* __restrict__ gbf) {
    int gid = blockIdx.x * 256 + threadIdx.x;      // handles 8 j's
    int j8 = gid & 15;
    int m  = gid >> 4;                             // b*128 + i
    int i  = m & 127;
    const float* src = G + (size_t)m * Vn + j8 * 8;
    float4 g0 = *(const float4*)src;
    float4 g1 = *(const float4*)(src + 4);
    float nb = nrow[m];
    float ge[8] = {g0.x, g0.y, g0.z, g0.w, g1.x, g1.y, g1.z, g1.w};
    u16 us[8];
    #pragma unroll
    for (int e = 0; e < 8; ++e) {
        float val = ge[e] + ((j8 * 8 + e) == i ? nb : 0.0f);
        us[e] = f2bf(val);
    }
    uint4 pack;
    pack.x = (unsigned)us[0] | ((unsigned)us[1] << 16);
    pack.y = (unsigned)us[2] | ((unsigned)us[3] << 16);
    pack.z = (unsigned)us[4] | ((unsigned)us[5] << 16);
    pack.w = (unsigned)us[6] | ((unsigned)us[7] << 16);
    *(uint4*)(gbf + (size_t)m * Vn + j8 * 8) = pack;
}

// ------------- transpose+split: src[K][N] f32 -> hi/lo[N][K] bf16 (per blockIdx.z mat) -------------
__global__ __launch_bounds__(256) void tsplit_kernel(const float* __restrict__ src,
                                                     u16* __restrict__ hi, u16* __restrict__ lo,
                                                     int N, int K) {
    __shared__ float tl[64][65];
    size_t mat = (size_t)blockIdx.z * K * N;
    int k0 = blockIdx.x * 64, n0 = blockIdx.y * 64;
    int t = threadIdx.x, c = t & 63, r4 = t >> 6;
    #pragma unroll
    for (int i = 0; i < 16; ++i) {
        int r = i * 4 + r4;
        tl[r][c] = src[mat + (size_t)(k0 + r) * N + n0 + c];
    }
    __syncthreads();
    #pragma unroll
    for (int i = 0; i < 16; ++i) {
        int nr = i * 4 + r4;
        float val = tl[c][nr];
        u16 h = f2bf(val);
        size_t idx = mat + (size_t)(n0 + nr) * K + k0 + c;
        hi[idx] = h;
        lo[idx] = f2bf(val - bf2f(h));
    }
}

// ---------------- feat: v = x@W_feat + b_feat (fp32 master only) ----------------
__global__ __launch_bounds__(256) void feat_kernel(const float* __restrict__ x,
                                                   const float* __restrict__ Wf,
                                                   const float* __restrict__ bf,
                                                   float* __restrict__ v) {
    __shared__ float xs[Fdim];
    int row = blockIdx.x;
    int h = threadIdx.x;
    if (h < Fdim) xs[h] = x[(size_t)row * Fdim + h];
    __syncthreads();
    float acc = bf[h];
    #pragma unroll 8
    for (int f = 0; f < Fdim; ++f) acc += xs[f] * Wf[f * Hdim + h];
    v[(size_t)row * Hdim + h] = acc;
}

// ======== quarter layer: block = (batch, d-quarter). grid (128,4) = 512 blocks, 512 thr ========
// GEMM1: D1[128 j][64 d] = v@W[:,quarter] (As chunks from v fp32, W direct from global)
// GEMM2: D2[64 d][128 i] = vp @ Gp^T (G in 32 regs); epi2 writes v_out[i][quarter].
// LDS 64KB (2 blocks/CU -> 16 waves/CU, 2x R6 occupancy):
//   AsH 16K @0 [128 j][128B], AsL @16K, VPH @32K [64 d][256B], VPL @48K.
// Same-batch blocks are 128 apart in linear bid => same XCD => v staging L2-hot after 1st.
// Register budget: acc1 16 + acc2 16 + gfr 32 + staging ~30 => ~100 <= 128 (R8-R11 law).
__global__ __launch_bounds__(512) void layer_quarter(const float* __restrict__ v_in,
                                                     float* __restrict__ v_out,
                                                     const u16* __restrict__ wthi,
                                                     const u16* __restrict__ wtlo,
                                                     const float* __restrict__ bias,
                                                     const u16* __restrict__ gbf,
                                                     const float* __restrict__ invdeg) {
    extern __shared__ char smem[];
    char* AsH = smem;                 // 16K
    char* AsL = smem + 16384;         // 16K
    char* VPH = smem + 32768;         // 16K
    char* VPL = smem + 49152;         // 16K

    const int tid = threadIdx.x, l = tid & 63, w = tid >> 6;
    const int whi = w >> 1, wlo = w & 1;   // GEMM1: whi=j-group(4x32), wlo=d-group(2x32)
                                           // GEMM2: whi=i-group(4x32), wlo=d-group(2x32)
    const int b  = blockIdx.x;             // batch (x-major => same-batch blocks same XCD)
    const int qd = blockIdx.y;             // d-quarter 0..3
    const int lr = l & 15, lq = l >> 4;
    const int swv = lr << 4;               // VP swizzle (rows 256B, ≡ lr mod 16)
    const int swa = (lr & 7) << 4;         // As swizzle (rows 128B, 8-row stripes)

    // ---- G fragments in registers (B-operand of GEMM2): rows i = whi*32+ni*16+lr ----
    const char* gb = (const char*)gbf + (size_t)b * 32768;
    short8 gfr[2][4];
    #pragma unroll
    for (int ni = 0; ni < 2; ++ni)
        #pragma unroll
        for (int kc = 0; kc < 4; ++kc)
            gfr[ni][kc] = *(const short8*)(gb + (size_t)(whi * 32 + ni * 16 + lr) * 256 + kc * 64 + lq * 16);

    float invd[2];
    #pragma unroll
    for (int ni = 0; ni < 2; ++ni) invd[ni] = invdeg[b * 128 + whi * 32 + ni * 16 + lr];

    const float* vb = v_in + (size_t)b * 128 * 256;
    float* vo = v_out + (size_t)b * 128 * 256;

    // staging geometry: thread covers row j = tid>>2, 16 floats at col (tid&3)*16
    const int sj = tid >> 2, scg = tid & 3;
    const int sbase = (sj * 128 + scg * 32);
    const int sswz = (sj & 7) << 4;

    f32x4 z = {0.f, 0.f, 0.f, 0.f};

    // ---- GEMM1: D1[j][d] = v @ W[:, qd], split-bf16, K=256 in 4 chunks of 64 ----
    f32x4 acc1[2][2];                     // [am j-frag][bn d-frag]
    #pragma unroll
    for (int am = 0; am < 2; ++am)
        #pragma unroll
        for (int bn = 0; bn < 2; ++bn) acc1[am][bn] = z;

    for (int c = 0; c < 4; ++c) {
        __syncthreads();                  // prev chunk's As reads complete
        {
            const float* p = vb + (size_t)sj * 256 + c * 64 + scg * 16;
            float4 f0 = *(const float4*)p;
            float4 f1 = *(const float4*)(p + 4);
            float4 f2 = *(const float4*)(p + 8);
            float4 f3 = *(const float4*)(p + 12);
            uint4 h, lo;
            splitpack(f0, f1, h, lo);
            *(uint4*)(AsH + ((sbase + 0) ^ sswz)) = h;
            *(uint4*)(AsL + ((sbase + 0) ^ sswz)) = lo;
            splitpack(f2, f3, h, lo);
            *(uint4*)(AsH + ((sbase + 16) ^ sswz)) = h;
            *(uint4*)(AsL + ((sbase + 16) ^ sswz)) = lo;
        }
        __syncthreads();
        #pragma unroll
        for (int kk = 0; kk < 2; ++kk) {
            short8 Ah[2], Al[2];
            #pragma unroll
            for (int am = 0; am < 2; ++am) {
                int off = ((whi * 32 + am * 16 + lr) * 128 + kk * 64 + lq * 16) ^ swa;
                Ah[am] = *(const short8*)(AsH + off);
                Al[am] = *(const short8*)(AsL + off);
            }
            #pragma unroll
            for (int bn = 0; bn < 2; ++bn) {
                size_t woff = (size_t)(qd * 64 + wlo * 32 + bn * 16 + lr) * 512 + (c * 2 + kk) * 64 + lq * 16;
                short8 Bh = *(const short8*)(wthi + 0) ;  // placeholder avoided below
                Bh = *(const short8*)((const char*)wthi + woff);
                short8 Bl = *(const short8*)((const char*)wtlo + woff);
                #pragma unroll
                for (int am = 0; am < 2; ++am) {
                    acc1[am][bn] = __builtin_amdgcn_mfma_f32_16x16x32_bf16(Ah[am], Bh, acc1[am][bn], 0, 0, 0);
                    acc1[am][bn] = __builtin_amdgcn_mfma_f32_16x16x32_bf16(Al[am], Bh, acc1[am][bn], 0, 0, 0);
                    acc1[am][bn] = __builtin_amdgcn_mfma_f32_16x16x32_bf16(Ah[am], Bl, acc1[am][bn], 0, 0, 0);
                }
            }
        }
    }

    // ---- epi1: vp = acc1 + bias -> split -> VP [d_local][j] ----
    // acc1 C-layout: row j = whi*32 + am*16 + lq*4 + r, col d_local = wlo*32 + bn*16 + lr
    #pragma unroll
    for (int am = 0; am < 2; ++am)
        #pragma unroll
        for (int bn = 0; bn < 2; ++bn) {
            int dl = wlo * 32 + bn * 16 + lr;
            float bvv = bias[qd * 64 + dl];
            int j0 = whi * 32 + am * 16 + lq * 4;
            f32x4 t = acc1[am][bn];
            t[0] += bvv; t[1] += bvv; t[2] += bvv; t[3] += bvv;
            ushort4 h4, l4;
            split4(t, h4, l4);
            int off = (dl * 256 + j0 * 2) ^ swv;
            *(ushort4*)(VPH + off) = h4;
            *(ushort4*)(VPL + off) = l4;
        }
    __syncthreads();

    // ---- GEMM2: D2[d][i] = sum_j vp[d][j] * Gp[i][j] (hi seg then lo seg) ----
    f32x4 acc2[2][2];                     // [mi d-frag][ni i-frag]
    #pragma unroll
    for (int mi = 0; mi < 2; ++mi) { acc2[mi][0] = z; acc2[mi][1] = z; }

    #pragma unroll
    for (int s = 0; s < 2; ++s) {
        const char* Aseg = s ? VPL : VPH;
        #pragma unroll
        for (int kc = 0; kc < 4; ++kc) {
            short8 Af[2];
            #pragma unroll
            for (int mi = 0; mi < 2; ++mi) {
                int off = ((wlo * 32 + mi * 16 + lr) * 256 + kc * 64 + lq * 16) ^ swv;
                Af[mi] = *(const short8*)(Aseg + off);
            }
            #pragma unroll
            for (int mi = 0; mi < 2; ++mi)
                #pragma unroll
                for (int ni = 0; ni < 2; ++ni)
                    acc2[mi][ni] = __builtin_amdgcn_mfma_f32_16x16x32_bf16(
                        Af[mi], gfr[ni][kc], acc2[mi][ni], 0, 0, 0);
        }
    }

    // ---- epi2: v_out[i][qd*64+dl] = v_in[i][qd*64+dl] + relu(D2 * invdeg)  (v_in L2-hot) ----
    // acc2 C-layout: row d_local = wlo*32 + mi*16 + lq*4 + r, col i = whi*32 + ni*16 + lr
    #pragma unroll
    for (int mi = 0; mi < 2; ++mi)
        #pragma unroll
        for (int ni = 0; ni < 2; ++ni) {
            int i = whi * 32 + ni * 16 + lr;
            int d0 = qd * 64 + wlo * 32 + mi * 16 + lq * 4;
            float4 c4 = *(const float4*)(vb + (size_t)i * 256 + d0);
            float4 o;
            o.x = c4.x + fmaxf(acc2[mi][ni][0] * invd[ni], 0.0f);
            o.y = c4.y + fmaxf(acc2[mi][ni][1] * invd[ni], 0.0f);
            o.z = c4.z + fmaxf(acc2[mi][ni][2] * invd[ni], 0.0f);
            o.w = c4.w + fmaxf(acc2[mi][ni][3] * invd[ni], 0.0f);
            *(float4*)(vo + (size_t)i * 256 + d0) = o;
        }
}

// ---------------- LayerNorm: read v fp32, write split h ----------------
__global__ __launch_bounds__(256) void ln_kernel(const float* __restrict__ v,
                                                 const float* __restrict__ g,
                                                 const float* __restrict__ beta,
                                                 u16* __restrict__ hhi,
                                                 u16* __restrict__ hlo) {
    __shared__ float sbuf[4];
    int row = blockIdx.x;
    int t = threadIdx.x;
    float x = v[(size_t)row * Hdim + t];
    float s = x;
    #pragma unroll
    for (int off = 32; off; off >>= 1) s += __shfl_down(s, off);
    int wid = t >> 6, lane = t & 63;
    if (lane == 0) sbuf[wid] = s;
    __syncthreads();
    float mu = (sbuf[0] + sbuf[1] + sbuf[2] + sbuf[3]) * (1.0f / Hdim);
    __syncthreads();
    float d = x - mu;
    float sq = d * d;
    #pragma unroll
    for (int off = 32; off; off >>= 1) sq += __shfl_down(sq, off);
    if (lane == 0) sbuf[wid] = sq;
    __syncthreads();
    float var = (sbuf[0] + sbuf[1] + sbuf[2] + sbuf[3]) * (1.0f / Hdim);
    float h = d * (1.0f / sqrtf(var + LN_EPS)) * g[t] + beta[t];
    size_t idx = (size_t)row * Hdim + t;
    u16 hb = f2bf(h);
    hhi[idx] = hb;
    hlo[idx] = f2bf(h - bf2f(hb));
}

// ---------------- fused final GEMM (direct staging + swizzle): part[m][nb] ----------------
__global__ __launch_bounds__(256) void gemm_fin_mfma(const u16* __restrict__ hhi,
                                                     const u16* __restrict__ hlo,
                                                     const u16* __restrict__ wfhi,
                                                     const u16* __restrict__ wflo,
                                                     const float* __restrict__ bfin,
                                                     const float* __restrict__ wout,
                                                     float* __restrict__ part) {
    __shared__ char smem[24576];
    char* As = smem;                 // 16384 (rows 128B)
    char* Bs = smem + 16384;         // 8192  (rows 128B)
    int tid = threadIdx.x, l = tid & 63, w = tid >> 6, wr = w >> 1, wc = w & 1;
    int m0 = blockIdx.x * 128, n0 = blockIdx.y * 64;
    const int lr = l & 15, lq = l >> 4, lkb = lq * 16;
    const int sw = (lr & 7) << 4;
    const char* segA[3] = {(const char*)hhi, (const char*)hlo, (const char*)hhi};
    const char* segB[3] = {(const char*)wfhi, (const char*)wfhi, (const char*)wflo};
    f32x4 z = {0.f, 0.f, 0.f, 0.f};
    f32x4 acc[4][2];
    #pragma unroll
    for (int mi = 0; mi < 4; ++mi) { acc[mi][0] = z; acc[mi][1] = z; }

    for (int q = 0; q < 12; ++q) {
        const char* A = segA[q >> 2] + (size_t)m0 * 512 + (q & 3) * 128;
        const char* B = segB[q >> 2] + (size_t)n0 * 512 + (q & 3) * 128;
        #pragma unroll
        for (int u = 0; u < 4; ++u) {
            int off = (u * 256 + tid) * 16;
            int row = off >> 7;
            *(uint4*)(As + (off ^ ((row & 7) << 4))) =
                *(const uint4*)(A + (size_t)row * 512 + (off & 127));
        }
        #pragma unroll
        for (int u = 0; u < 2; ++u) {
            int off = (u * 256 + tid) * 16;
            int row = off >> 7;
            *(uint4*)(Bs + (off ^ ((row & 7) << 4))) =
                *(const uint4*)(B + (size_t)row * 512 + (off & 127));
        }
        __syncthreads();
        #pragma unroll
        for (int kk = 0; kk < 2; ++kk) {
            short8 a[4], b2[2];
            #pragma unroll
            for (int mi = 0; mi < 4; ++mi)
                a[mi] = *(const short8*)(As + (((wr * 64 + mi * 16 + lr) * 128 + kk * 64 + lkb) ^ sw));
            #pragma unroll
            for (int ni = 0; ni < 2; ++ni)
                b2[ni] = *(const short8*)(Bs + (((wc * 32 + ni * 16 + lr) * 128 + kk * 64 + lkb) ^ sw));
            #pragma unroll
            for (int mi = 0; mi < 4; ++mi)
                #pragma unroll
                for (int ni = 0; ni < 2; ++ni)
                    acc[mi][ni] = __builtin_amdgcn_mfma_f32_16x16x32_bf16(a[mi], b2[ni],
                                                                         acc[mi][ni], 0, 0, 0);
        }
        __syncthreads();
    }
    float rs[4][4];
    #pragma unroll
    for (int mi = 0; mi < 4; ++mi)
        #pragma unroll
        for (int r = 0; r < 4; ++r) rs[mi][r] = 0.0f;
    #pragma unroll
    for (int ni = 0; ni < 2; ++ni) {
        int n = n0 + wc * 32 + ni * 16 + lr;
        float bvv = bfin[n], wo = wout[n];
        #pragma unroll
        for (int mi = 0; mi < 4; ++mi)
            #pragma unroll
            for (int r = 0; r < 4; ++r)
                rs[mi][r] += fmaxf(acc[mi][ni][r] + bvv, 0.0f) * wo;
    }
    float* red = (float*)smem;          // [128][33] floats; loop ended with barrier
    #pragma unroll
    for (int mi = 0; mi < 4; ++mi)
        #pragma unroll
        for (int r = 0; r < 4; ++r) {
            int row = wr * 64 + mi * 16 + lq * 4 + r;
            red[row * 33 + wc * 16 + lr] = rs[mi][r];
        }
    __syncthreads();
    if (tid < 128) {
        float s = 0.0f;
        #pragma unroll
        for (int c = 0; c < 32; ++c) s += red[tid * 33 + c];
        part[(size_t)(m0 + tid) * 16 + blockIdx.y] = s;
    }
}

// ---------------- final reduce ----------------
__global__ __launch_bounds__(256) void final_kernel(const float* __restrict__ part,
                                                    const float* __restrict__ bo,
                                                    float* __restrict__ out) {
    int i = blockIdx.x * 256 + threadIdx.x;
    float s = bo[0];
    #pragma unroll
    for (int t = 0; t < 16; ++t) s += part[(size_t)i * 16 + t];
    out[i] = s;
}

extern "C" void kernel_launch(void* const* d_in, const int* in_sizes, int n_in,
                              void* d_out, int out_size, void* d_ws, size_t ws_size,
                              hipStream_t stream) {
    const float* x        = (const float*)d_in[0];
    const float* G        = (const float*)d_in[1];
    const float* W_feat   = (const float*)d_in[2];
    const float* b_feat   = (const float*)d_in[3];
    const float* W_layers = (const float*)d_in[4];
    const float* b_layers = (const float*)d_in[5];
    const float* ln_g     = (const float*)d_in[6];
    const float* ln_b     = (const float*)d_in[7];
    const float* W_fin    = (const float*)d_in[8];
    const float* b_fin    = (const float*)d_in[9];
    const float* W_out    = (const float*)d_in[10];
    const float* b_out    = (const float*)d_in[11];
    float* out = (float*)d_out;

    const int M = Bsz * Vn;                          // 16384
    char* ws = (char*)d_ws;
    float* v0     = (float*)ws;                      ws += (size_t)M * Hdim * 4;     // 16 MB
    float* v1     = (float*)ws;                      ws += (size_t)M * Hdim * 4;     // 16 MB
    u16*   gbf    = (u16*)ws;                        ws += (size_t)Bsz * Vn * Vn * 2;   // 4 MB
    u16*   wthi   = (u16*)ws;                        ws += (size_t)Lnum * Hdim * Hdim * 2; // 4 MB
    u16*   wtlo   = (u16*)ws;                        ws += (size_t)Lnum * Hdim * Hdim * 2; // 4 MB
    u16*   wfhi   = (u16*)ws;                        ws += (size_t)FLdim * Hdim * 2;  // 0.5 MB
    u16*   wflo   = (u16*)ws;                        ws += (size_t)FLdim * Hdim * 2;  // 0.5 MB
    float* nrow   = (float*)ws;                      ws += (size_t)M * 4;
    float* invdeg = (float*)ws;                      ws += (size_t)M * 4;
    float* part   = (float*)ws;                      ws += (size_t)M * 16 * 4;        // 1 MB

    // h splits alias v1 (dead after the layer loop: 32 layers end in v0)
    u16* hh = (u16*)v1;
    u16* hl = hh + (size_t)M * Hdim;

    float* vv[2] = {v0, v1};

    hipFuncSetAttribute((const void*)layer_quarter,
                        hipFuncAttributeMaxDynamicSharedMemorySize, 65536);

    rowsum_kernel<<<M / 4, 256, 0, stream>>>(G, nrow, invdeg);
    gbf_kernel<<<(Bsz * Vn * 16) / 256, 256, 0, stream>>>(G, nrow, gbf);
    tsplit_kernel<<<dim3(4, 4, Lnum), 256, 0, stream>>>(W_layers, wthi, wtlo, Hdim, Hdim);
    tsplit_kernel<<<dim3(4, 16, 1), 256, 0, stream>>>(W_fin, wfhi, wflo, FLdim, Hdim);
    feat_kernel<<<M, 256, 0, stream>>>(x, W_feat, b_feat, v0);

    for (int l = 0; l < Lnum; ++l) {
        int in = l & 1;                  // l=0 reads v0 writes v1; alternate
        layer_quarter<<<dim3(Bsz, 4), 512, 65536, stream>>>(
            vv[in], vv[in ^ 1],
            wthi + (size_t)l * Hdim * Hdim, wtlo + (size_t)l * Hdim * Hdim,
            b_layers + (size_t)l * Hdim,
            gbf, invdeg);
    }

    ln_kernel<<<M, 256, 0, stream>>>(v0, ln_g, ln_b, hh, hl);
    gemm_fin_mfma<<<dim3(M / 128, FLdim / 64), 256, 0, stream>>>(
        hh, hl, wfhi, wflo, b_fin, W_out, part);
    final_kernel<<<M / 256, 256, 0, stream>>>(part, b_out, out);
}